// Round 3
// baseline (77.033 us; speedup 1.0000x reference)
//
#include <hip/hip_runtime.h>

// LIF integrate-fire-reset over the time axis.
// x: [B=64, C=2048, T=256] f32 row-major -> 131072 rows of 256 contiguous floats.
// u_t = TAU*u_{t-1}*(1-s_{t-1}) + x_t ; s_t = (u_t > VTH).
//
// Occupancy is problem-capped at 8 waves/CU (131072 rows / 64 rows-per-wave /
// 256 CU), so this version makes every wave independent and deeply prefetched:
//   - ONE WAVE PER BLOCK, zero s_barrier: LDS transpose is wave-synchronous
//     (explicit lgkmcnt(0) fence between ds_write and ds_read only),
//   - register prefetch DEPTH 2: chunk k+2's global loads issue at chunk k,
//     ~2 chunk-periods (>1600 cyc) before staging consumes them -> no vmcnt
//     stall on HBM-miss latency (~900 cyc),
//   - LDS stride 36 words/row: conflict-free b128 writes and reads (verified
//     0 bank conflicts in R1/R2),
//   - spikes packed to 32-bit masks, exchanged via wave shuffle, expanded to
//     coalesced nontemporal float4 stores.

#define T_LEN 256
#define TQ 64              // float4 per row
#define NCH 8              // 8 chunks of 32 timesteps
#define WPB 64             // threads per block == rows per block (one wave)
#define XS_STRIDE 36       // LDS words per row (32 + 4 pad)

#define TAU 0.25f
#define VTH 0.5f

typedef float f32x4 __attribute__((ext_vector_type(4)));

__global__ __launch_bounds__(WPB, 2)
void lif_kernel(const float* __restrict__ x, float* __restrict__ out) {
    __shared__ __align__(16) float xs[2][WPB * XS_STRIDE];  // 2 x 9216 B

    const int lane = threadIdx.x;            // 0..63
    const long rbase = (long)blockIdx.x * WPB;

    const float4* __restrict__ x4 = reinterpret_cast<const float4*>(x);

    const int qs = lane & 7;   // float4 slot this lane stages
    const int rs = lane >> 3;  // base staging row (stride 8 per i)

    // ---- prologue: prefetch chunks 0 and 1 into registers ----
    float4 p[2][8];
    #pragma unroll
    for (int i = 0; i < 8; ++i)
        p[0][i] = x4[(rbase + rs + i * 8) * TQ + 0 * 8 + qs];
    #pragma unroll
    for (int i = 0; i < 8; ++i)
        p[1][i] = x4[(rbase + rs + i * 8) * TQ + 1 * 8 + qs];

    float u = 0.0f;
    bool sprev = false;

    #pragma unroll
    for (int k = 0; k < NCH; ++k) {           // k is compile-time (fully unrolled)
        float* buf = xs[k & 1];

        // ---- stage chunk k: regs -> LDS (b128, conflict-free) ----
        #pragma unroll
        for (int i = 0; i < 8; ++i)
            *reinterpret_cast<float4*>(&buf[(rs + i * 8) * XS_STRIDE + 4 * qs]) = p[k & 1][i];

        // wave-synchronous fence: all lanes' ds_writes retired before any ds_read
        asm volatile("s_waitcnt lgkmcnt(0)" ::: "memory");
        __builtin_amdgcn_sched_barrier(0);

        // ---- read own row from LDS ----
        float4 v[8];
        #pragma unroll
        for (int i = 0; i < 8; ++i)
            v[i] = *reinterpret_cast<const float4*>(&buf[lane * XS_STRIDE + 4 * i]);

        // ---- prefetch chunk k+2 into the register slot just freed ----
        if (k + 2 < NCH) {
            #pragma unroll
            for (int i = 0; i < 8; ++i)
                p[k & 1][i] = x4[(rbase + rs + i * 8) * TQ + (k + 2) * 8 + qs];
        }

        // ---- 32 sequential LIF steps, bit-exact vs reference ----
        unsigned int m = 0;
        #pragma unroll
        for (int i = 0; i < 8; ++i) {
            float e[4] = { v[i].x, v[i].y, v[i].z, v[i].w };
            #pragma unroll
            for (int j = 0; j < 4; ++j) {
                float um = sprev ? 0.0f : __fmul_rn(TAU, u);
                u = __fadd_rn(um, e[j]);
                sprev = u > VTH;
                m |= (sprev ? 1u : 0u) << (i * 4 + j);
            }
        }

        // ---- wave-local mask exchange + nontemporal coalesced stores ----
        #pragma unroll
        for (int i = 0; i < 8; ++i) {
            int rowl = i * 8 + (lane >> 3);                      // row within wave
            unsigned int mr = (unsigned int)__shfl((int)m, rowl, 64);
            int toff = 4 * (lane & 7);
            f32x4 o;
            o[0] = ((mr >> (toff + 0)) & 1u) ? 1.0f : 0.0f;
            o[1] = ((mr >> (toff + 1)) & 1u) ? 1.0f : 0.0f;
            o[2] = ((mr >> (toff + 2)) & 1u) ? 1.0f : 0.0f;
            o[3] = ((mr >> (toff + 3)) & 1u) ? 1.0f : 0.0f;
            long gq = (rbase + rowl) * (long)TQ + k * 8 + (lane & 7);
            __builtin_nontemporal_store(o, reinterpret_cast<f32x4*>(out) + gq);
        }
        // Double-buffered LDS: iter k+1 writes the other buffer; this buffer's
        // reads completed before our own compute (lgkm drained by v-use), and
        // wave in-order issue makes the k+2 overwrite safe.
    }
}

extern "C" void kernel_launch(void* const* d_in, const int* in_sizes, int n_in,
                              void* d_out, int out_size, void* d_ws, size_t ws_size,
                              hipStream_t stream) {
    const float* x = (const float*)d_in[0];
    float* out = (float*)d_out;
    const int total = in_sizes[0];      // 64*2048*256
    const int nrows = total / T_LEN;    // 131072
    const int blocks = nrows / WPB;     // 2048
    lif_kernel<<<blocks, WPB, 0, stream>>>(x, out);
}